// Round 8
// baseline (264.969 us; speedup 1.0000x reference)
//
#include <hip/hip_runtime.h>
#include <hip/hip_bf16.h>
#include <hip/hip_cooperative_groups.h>
#include <math.h>

namespace cg = cooperative_groups;

#define BB 8
#define NN 2048
#define INC 256
#define CC 128
#define NE 65536
#define CAP 128
#define MROWS (BB*NN)
#define BN_EPS 1e-5f
#define NT 9              // output col-tiles of 16 (8 -> hm, 1 -> s+pad)
#define NKC 8             // K chunks of 32 (K=256)
#define NFRAG (NT*NKC*64) // 4608 pre-packed fragments (72 KB)
#define FPSCALE 4194304.0 // 2^22 fixed-point scale for deterministic BN atomics
#define SMEM_BYTES 22912

typedef unsigned int uint32;
typedef unsigned long long u64;
typedef __attribute__((ext_vector_type(8))) short short8;
typedef __attribute__((ext_vector_type(4))) float f32x4;

__device__ inline ushort f2bf(float f) {
  __hip_bfloat16 b = __float2bfloat16(f);   // HW cvt, RNE
  return reinterpret_cast<ushort&>(b);
}
__device__ inline float bf2f(ushort h) {
  return __uint_as_float(((uint32)h) << 16);
}

__device__ inline void load_edge(const void* ei, int is64, int e, int& s, int& d) {
  if (is64) {
    const long long* p = (const long long*)ei;
    s = (int)p[e]; d = (int)p[NE + e];
  } else {
    const int* p = (const int*)ei;
    s = p[e]; d = p[NE + e];
  }
}

__device__ inline float edge_e(f32x4 ss, f32x4 sd) {
  float sum = 0.0f;
  #pragma unroll
  for (int h = 0; h < 4; ++h) {
    float v = ss[h] + sd[h];
    sum += (v > 0.0f) ? v : 0.2f * v;
  }
  return 0.25f * sum;
}

// ============ phase 0: W -> packed MFMA frags; detect int64; zero cnt/bins ===
// block m (0..31) owns input rows [8m,8m+8) == frag k-slice (kc=m>>2, g=m&3).
__device__ inline void phase0_prep(char* smem, int m, int tid,
                                   const float* __restrict__ W,
                                   const float* __restrict__ a,
                                   const int* __restrict__ ei32,
                                   uint4* __restrict__ pack,
                                   int* __restrict__ flag,
                                   int* __restrict__ row_cnt,
                                   u64* __restrict__ bins) {
  float (*Wl)[520]  = (float(*)[520])(smem);            // 16640 B
  float (*Wms)[132] = (float(*)[132])(smem + 16640);    //  4224 B
  float (*Was)[8]   = (float(*)[8])(smem + 20864);      //   256 B
  float* av         = (float*)(smem + 21120);           //  1024 B
  if (m < 8) row_cnt[m * 256 + tid] = 0;
  if (m == 8) {
    #pragma unroll
    for (int i = 0; i < 8; ++i) bins[tid * 8 + i] = 0ull;
  }
  if (m == 0 && tid == 0) {
    int nz = 0;
    for (int t = 1; t < 128; t += 2) nz |= (ei32[t] != 0);
    *flag = nz ? 0 : 1;      // 1 => int64 layout
  }
  av[tid] = a[tid];
  const float4* Wg = (const float4*)(W + (size_t)m * 8 * 512);
  #pragma unroll
  for (int i = 0; i < 4; ++i) {
    int idx = tid + i * 256;           // 0..1023 float4s = 8 rows x 128
    int r = idx >> 7, c4 = idx & 127;
    *(float4*)&Wl[r][c4 * 4] = Wg[idx];
  }
  __syncthreads();
  {
    int c = tid & 127, half = tid >> 7;
    #pragma unroll
    for (int ii = 0; ii < 4; ++ii) {
      int r = half * 4 + ii;
      Wms[r][c] = 0.25f * (Wl[r][c] + Wl[r][128 + c] + Wl[r][256 + c] + Wl[r][384 + c]);
    }
  }
  {
    int i8 = tid >> 5, c2 = tid & 31;
    float p[8];
    #pragma unroll
    for (int j = 0; j < 8; ++j) p[j] = 0.0f;
    #pragma unroll
    for (int t4 = 0; t4 < 4; ++t4) {
      int cc = c2 + t4 * 32;
      float asrc = av[cc], adst = av[128 + cc];
      #pragma unroll
      for (int h = 0; h < 4; ++h) {
        float w = Wl[i8][h * 128 + cc];
        p[h] += w * asrc;
        p[4 + h] += w * adst;
      }
    }
    #pragma unroll
    for (int off = 16; off > 0; off >>= 1)
      #pragma unroll
      for (int j = 0; j < 8; ++j) p[j] += __shfl_xor(p[j], off, 64);
    if (c2 < 8) Was[i8][c2] = p[c2];
  }
  __syncthreads();
  if (tid < 144) {
    int t = tid >> 4, l16 = tid & 15;
    int cch = t * 16 + l16;
    int kc = m >> 2, g = m & 3;
    uint32 h[8];
    #pragma unroll
    for (int j = 0; j < 8; ++j) {
      float v = 0.0f;
      if (cch < CC) v = Wms[j][cch];
      else if (cch < CC + 8) v = Was[j][cch - CC];
      h[j] = (uint32)f2bf(v);
    }
    uint4 u;
    u.x = h[0] | (h[1] << 16);
    u.y = h[2] | (h[3] << 16);
    u.z = h[4] | (h[5] << 16);
    u.w = h[6] | (h[7] << 16);
    pack[(t * NKC + kc) * 64 + g * 16 + l16] = u;
  }
}

// ============ phase 1: MFMA GEMM for one 16-row tile =========================
// hm(bf16)[16384][128] = x @ Wm ; s(f32)[16384][8] = x @ Wa.
// 4 waves: wave wv computes tiles {2wv,2wv+1}; wave 3 also tile 8 (E).
__device__ inline void phase1_gemm(int tile, int tid,
                                   const float* __restrict__ x,
                                   const uint4* __restrict__ pack,
                                   ushort* __restrict__ hm,
                                   float* __restrict__ s) {
  int lane = tid & 63, wv = tid >> 6;
  int g = lane >> 4;
  int xrow = tile * 16 + (lane & 15);
  const float* xr = x + (size_t)xrow * INC;
  short8 xf[8];
  #pragma unroll
  for (int kc = 0; kc < 8; ++kc) {
    f32x4 xa = *(const f32x4*)(xr + kc * 32 + g * 8);
    f32x4 xb = *(const f32x4*)(xr + kc * 32 + g * 8 + 4);
    short8 t;
    t[0] = (short)f2bf(xa[0]); t[1] = (short)f2bf(xa[1]);
    t[2] = (short)f2bf(xa[2]); t[3] = (short)f2bf(xa[3]);
    t[4] = (short)f2bf(xb[0]); t[5] = (short)f2bf(xb[1]);
    t[6] = (short)f2bf(xb[2]); t[7] = (short)f2bf(xb[3]);
    xf[kc] = t;
  }
  int t0 = wv * 2;
  f32x4 acc0 = (f32x4)(0.0f), acc1 = (f32x4)(0.0f), accE = (f32x4)(0.0f);
  const short8* fr = (const short8*)pack;
  #pragma unroll
  for (int kc = 0; kc < NKC; ++kc) {
    short8 af0 = fr[((t0 + 0) * NKC + kc) * 64 + lane];
    acc0 = __builtin_amdgcn_mfma_f32_16x16x32_bf16(af0, xf[kc], acc0, 0, 0, 0);
    short8 af1 = fr[((t0 + 1) * NKC + kc) * 64 + lane];
    acc1 = __builtin_amdgcn_mfma_f32_16x16x32_bf16(af1, xf[kc], acc1, 0, 0, 0);
    if (wv == 3) {
      short8 ae = fr[(8 * NKC + kc) * 64 + lane];
      accE = __builtin_amdgcn_mfma_f32_16x16x32_bf16(ae, xf[kc], accE, 0, 0, 0);
    }
  }
  // D layout: row(ch-in-tile) = 4*g + reg, col = lane&15
  ushort* hrow = hm + (size_t)xrow * CC;
  uint32 p0 = (uint32)f2bf(acc0[0]) | ((uint32)f2bf(acc0[1]) << 16);
  uint32 p1 = (uint32)f2bf(acc0[2]) | ((uint32)f2bf(acc0[3]) << 16);
  *(uint2*)(hrow + (t0 + 0) * 16 + g * 4) = make_uint2(p0, p1);
  p0 = (uint32)f2bf(acc1[0]) | ((uint32)f2bf(acc1[1]) << 16);
  p1 = (uint32)f2bf(acc1[2]) | ((uint32)f2bf(acc1[3]) << 16);
  *(uint2*)(hrow + (t0 + 1) * 16 + g * 4) = make_uint2(p0, p1);
  if (wv == 3 && g < 2) {
    *(f32x4*)(s + (size_t)xrow * 8 + g * 4) = accE;
  }
}

// ============ phase 2: dedupe+sort+e+softmax+aggregate+BN-partials (1 row) ===
__device__ inline void phase2_agg(char* smem, int d, int tid,
                                  const int* __restrict__ row_cnt,
                                  const int* __restrict__ row_src,
                                  const float* __restrict__ s,
                                  const uint32* __restrict__ hm32,
                                  uint32* __restrict__ hout,
                                  u64* __restrict__ bins) {
  int*   rsrc = (int*)(smem);                         //  512 B
  int*   csrc = (int*)(smem + 512);                   //  512 B
  float (*swgt)[CAP] = (float(*)[CAP])(smem + 1024);  // 4096 B
  f32x4* red  = (f32x4*)(smem + 5120);                // 4096 B
  int*   wcnt = (int*)(smem + 9216);                  //    8 B
  int lane = tid & 63, wv = tid >> 6;
  __syncthreads();   // guard smem reuse across calls
  int k0 = row_cnt[d]; if (k0 > CAP) k0 = CAP;
  if (tid < k0) rsrc[tid] = row_src[d * CAP + tid];
  __syncthreads();
  // dedupe by src (duplicate (src,dst) edges have identical e-values)
  int keep = 0;
  if (tid < k0) {
    keep = 1;
    int sv = rsrc[tid];
    for (int q = 0; q < tid; ++q) if (rsrc[q] == sv) { keep = 0; break; }
  }
  u64 mask = __ballot(keep);
  int pos = __popcll(mask & ((1ull << lane) - 1ull));
  if (lane == 0 && wv < 2) wcnt[wv] = (int)__popcll(mask);
  __syncthreads();
  int base = (wv == 1) ? wcnt[0] : 0;
  if (keep) csrc[base + pos] = rsrc[tid];
  __syncthreads();
  int kd = wcnt[0] + wcnt[1];
  // rank-sort by src value (unique) -> deterministic reduction order
  if (tid < kd) {
    int sv = csrc[tid], r = 0;
    for (int q = 0; q < kd; ++q) r += (csrc[q] < sv) ? 1 : 0;
    rsrc[r] = sv;
  }
  __syncthreads();

  int b0 = wv, b1 = wv + 4;
  const float* sb0 = s + (size_t)b0 * NN * 8;
  const float* sb1 = s + (size_t)b1 * NN * 8;
  f32x4 sd0 = *(const f32x4*)(sb0 + (size_t)d * 8 + 4);
  f32x4 sd1 = *(const f32x4*)(sb1 + (size_t)d * 8 + 4);
  float v00 = -INFINITY, v01 = -INFINITY, v10 = -INFINITY, v11 = -INFINITY;
  if (lane < kd) {
    int r = rsrc[lane];
    f32x4 s0 = *(const f32x4*)(sb0 + (size_t)r * 8);
    f32x4 s1 = *(const f32x4*)(sb1 + (size_t)r * 8);
    v00 = edge_e(s0, sd0);
    v10 = edge_e(s1, sd1);
  }
  if (lane + 64 < kd) {
    int r = rsrc[lane + 64];
    f32x4 s0 = *(const f32x4*)(sb0 + (size_t)r * 8);
    f32x4 s1 = *(const f32x4*)(sb1 + (size_t)r * 8);
    v01 = edge_e(s0, sd0);
    v11 = edge_e(s1, sd1);
  }
  float m0 = fmaxf(v00, v01), m1 = fmaxf(v10, v11);
  #pragma unroll
  for (int off = 32; off > 0; off >>= 1) {
    m0 = fmaxf(m0, __shfl_xor(m0, off, 64));
    m1 = fmaxf(m1, __shfl_xor(m1, off, 64));
  }
  float e00 = (lane < kd)      ? expf(v00 - m0) : 0.0f;
  float e01 = (lane + 64 < kd) ? expf(v01 - m0) : 0.0f;
  float e10 = (lane < kd)      ? expf(v10 - m1) : 0.0f;
  float e11 = (lane + 64 < kd) ? expf(v11 - m1) : 0.0f;
  float sum0 = e00 + e01, sum1 = e10 + e11;
  #pragma unroll
  for (int off = 32; off > 0; off >>= 1) {
    sum0 += __shfl_xor(sum0, off, 64);
    sum1 += __shfl_xor(sum1, off, 64);
  }
  float inv0 = (kd > 0) ? 1.0f / sum0 : 0.0f;
  float inv1 = (kd > 0) ? 1.0f / sum1 : 0.0f;
  swgt[b0][lane]      = e00 * inv0;
  swgt[b0][lane + 64] = e01 * inv0;
  swgt[b1][lane]      = e10 * inv1;
  swgt[b1][lane + 64] = e11 * inv1;

  float a0 = 0.0f, a1 = 0.0f, a2 = 0.0f, a3 = 0.0f;
  const uint32* hb0 = hm32 + (size_t)b0 * NN * (CC / 2);
  const uint32* hb1 = hm32 + (size_t)b1 * NN * (CC / 2);
  #pragma unroll 4
  for (int j = 0; j < kd; ++j) {
    int r = rsrc[j];
    float w0 = swgt[b0][j], w1 = swgt[b1][j];
    uint32 u0 = hb0[(size_t)r * (CC / 2) + lane];
    uint32 u1 = hb1[(size_t)r * (CC / 2) + lane];
    a0 += w0 * bf2f((ushort)(u0 & 0xffffu));
    a1 += w0 * bf2f((ushort)(u0 >> 16));
    a2 += w1 * bf2f((ushort)(u1 & 0xffffu));
    a3 += w1 * bf2f((ushort)(u1 >> 16));
  }
  hout[((size_t)b0 * NN + d) * (CC / 2) + lane] =
      (uint32)f2bf(a0) | ((uint32)f2bf(a1) << 16);
  hout[((size_t)b1 * NN + d) * (CC / 2) + lane] =
      (uint32)f2bf(a2) | ((uint32)f2bf(a3) << 16);

  // block-reduce BN partials, fixed-point i64 atomics (deterministic)
  f32x4 r4;
  r4[0] = a0 + a2; r4[1] = a0 * a0 + a2 * a2;
  r4[2] = a1 + a3; r4[3] = a1 * a1 + a3 * a3;
  red[tid] = r4;
  __syncthreads();
  if (wv == 0) {
    f32x4 t = red[lane] + red[lane + 64] + red[lane + 128] + red[lane + 192];
    u64* bb = bins + (size_t)(d & 7) * (CC * 2);
    atomicAdd(&bb[4 * lane + 0], (u64)(long long)llrint((double)t[0] * FPSCALE));
    atomicAdd(&bb[4 * lane + 1], (u64)(long long)llrint((double)t[1] * FPSCALE));
    atomicAdd(&bb[4 * lane + 2], (u64)(long long)llrint((double)t[2] * FPSCALE));
    atomicAdd(&bb[4 * lane + 3], (u64)(long long)llrint((double)t[3] * FPSCALE));
  }
}

// ============ phase 3: BN finalize (redundant/block) + ELU ===================
__device__ inline void phase3_bn(char* smem, int tid,
                                 const u64* __restrict__ bins,
                                 const float* __restrict__ gamma,
                                 const float* __restrict__ beta) {
  float* bsc = (float*)(smem);
  float* bsh = (float*)(smem + 512);
  if (tid < CC) {
    long long S = 0, Q = 0;
    #pragma unroll
    for (int bin = 0; bin < 8; ++bin) {
      S += (long long)bins[bin * (CC * 2) + 2 * tid];
      Q += (long long)bins[bin * (CC * 2) + 2 * tid + 1];
    }
    double mean = (double)S / FPSCALE / (double)MROWS;
    double var  = (double)Q / FPSCALE / (double)MROWS - mean * mean;
    if (var < 0.0) var = 0.0;
    float scale = gamma[tid] / sqrtf((float)var + BN_EPS);
    bsc[tid] = scale;
    bsh[tid] = beta[tid] - (float)mean * scale;
  }
  __syncthreads();
}
__device__ inline void phase3_elu(char* smem, int pp, int tid,
                                  const uint32* __restrict__ hout,
                                  float* __restrict__ out) {
  float* bsc = (float*)(smem);
  float* bsh = (float*)(smem + 512);
  int pbase = pp * 1024 + tid;
  #pragma unroll
  for (int i = 0; i < 4; ++i) {
    int p = pbase + i * 256;      // pair index
    int cp = p & 63;
    uint32 u = hout[p];
    float y0 = bf2f((ushort)(u & 0xffffu)) * bsc[2 * cp]     + bsh[2 * cp];
    float y1 = bf2f((ushort)(u >> 16))     * bsc[2 * cp + 1] + bsh[2 * cp + 1];
    float2 o;
    o.x = (y0 > 0.0f) ? y0 : expm1f(y0);
    o.y = (y1 > 0.0f) ? y1 : expm1f(y1);
    *(float2*)(out + 2 * (size_t)p) = o;
  }
}

// ============ fused cooperative kernel (grid-size agnostic) ==================
__global__ __launch_bounds__(256, 4) void k_fused(
    const float* __restrict__ x, const void* __restrict__ ei,
    const float* __restrict__ W, const float* __restrict__ a,
    const float* __restrict__ gamma, const float* __restrict__ beta,
    float* __restrict__ out,
    ushort* __restrict__ hm, uint32* __restrict__ hout,
    float* __restrict__ s, uint4* __restrict__ pack,
    u64* __restrict__ bins, int* __restrict__ flag,
    int* __restrict__ row_cnt, int* __restrict__ row_src) {
  cg::grid_group grid = cg::this_grid();
  __shared__ __align__(16) char smem[SMEM_BYTES];
  int blk = blockIdx.x, tid = threadIdx.x, G = gridDim.x;

  if (blk < 32)
    phase0_prep(smem, blk, tid, W, a, (const int*)ei, pack, flag, row_cnt, bins);
  grid.sync();

  {
    int is64 = *flag;
    for (int c = blk; c < NE / 256; c += G) {
      int e = c * 256 + tid;
      int src, dst;
      load_edge(ei, is64, e, src, dst);
      int pos = atomicAdd(&row_cnt[dst], 1);
      if (pos < CAP) row_src[dst * CAP + pos] = src;
    }
  }
  for (int tile = blk; tile < MROWS / 16; tile += G)
    phase1_gemm(tile, tid, x, pack, hm, s);
  grid.sync();

  for (int d = blk; d < NN; d += G)
    phase2_agg(smem, d, tid, row_cnt, row_src, s, (const uint32*)hm, hout, bins);
  grid.sync();

  phase3_bn(smem, tid, bins, gamma, beta);
  for (int pp = blk; pp < 1024; pp += G)
    phase3_elu(smem, pp, tid, hout, out);
}

// ============ fallback standalone kernels (same phase functions) =============
__global__ __launch_bounds__(256) void sk_prep(const float* __restrict__ W,
                                               const float* __restrict__ a,
                                               const int* __restrict__ ei32,
                                               uint4* __restrict__ pack,
                                               int* __restrict__ flag,
                                               int* __restrict__ row_cnt,
                                               u64* __restrict__ bins) {
  __shared__ __align__(16) char smem[SMEM_BYTES];
  phase0_prep(smem, blockIdx.x, threadIdx.x, W, a, ei32, pack, flag, row_cnt, bins);
}
__global__ __launch_bounds__(256) void sk_gemm(const float* __restrict__ x,
                                               const uint4* __restrict__ pack,
                                               const void* __restrict__ ei,
                                               const int* __restrict__ flag,
                                               ushort* __restrict__ hm,
                                               float* __restrict__ s,
                                               int* __restrict__ row_cnt,
                                               int* __restrict__ row_src) {
  if (threadIdx.x < 64) {
    int e = blockIdx.x * 64 + threadIdx.x;
    int is64 = *flag;
    int src, dst;
    load_edge(ei, is64, e, src, dst);
    int pos = atomicAdd(&row_cnt[dst], 1);
    if (pos < CAP) row_src[dst * CAP + pos] = src;
  }
  phase1_gemm(blockIdx.x, threadIdx.x, x, pack, hm, s);
}
__global__ __launch_bounds__(256) void sk_agg(const int* __restrict__ row_cnt,
                                              const int* __restrict__ row_src,
                                              const float* __restrict__ s,
                                              const uint32* __restrict__ hm32,
                                              uint32* __restrict__ hout,
                                              u64* __restrict__ bins) {
  __shared__ __align__(16) char smem[9224];
  phase2_agg(smem, blockIdx.x, threadIdx.x, row_cnt, row_src, s, hm32, hout, bins);
}
__global__ __launch_bounds__(256) void sk_elu(const uint32* __restrict__ hout,
                                              const u64* __restrict__ bins,
                                              const float* __restrict__ gamma,
                                              const float* __restrict__ beta,
                                              float* __restrict__ out) {
  __shared__ __align__(16) char smem[1024];
  phase3_bn(smem, threadIdx.x, bins, gamma, beta);
  phase3_elu(smem, blockIdx.x, threadIdx.x, hout, out);
}

extern "C" void kernel_launch(void* const* d_in, const int* in_sizes, int n_in,
                              void* d_out, int out_size, void* d_ws, size_t ws_size,
                              hipStream_t stream) {
  const float* x     = (const float*)d_in[0];
  const void*  ei    = d_in[1];
  const float* W     = (const float*)d_in[2];
  const float* a     = (const float*)d_in[3];
  const float* gamma = (const float*)d_in[4];
  const float* beta  = (const float*)d_in[5];
  float* out = (float*)d_out;

  char* p = (char*)d_ws;
  ushort* hm   = (ushort*)p; p += (size_t)MROWS * CC * 2;  // 4 MB (bf16)
  uint32* hout = (uint32*)p; p += (size_t)MROWS * CC * 2;  // 4 MB (bf16 pairs)
  float* s    = (float*)p; p += (size_t)MROWS * 8 * 4;     // 512 KB
  uint4* pack = (uint4*)p; p += (size_t)NFRAG * 16;        // 72 KB
  u64* bins   = (u64*)p;   p += 8 * CC * 2 * 8;            // 16 KB
  int* flag   = (int*)p;   p += 256;
  int* row_cnt  = (int*)p; p += NN * 4;
  int* row_src  = (int*)p; p += (size_t)NN * CAP * 4;      // 1 MB

  // host-side, capture-safe queries; deterministic on a given device
  int dev = 0; (void)hipGetDevice(&dev);
  int coop = 0; (void)hipDeviceGetAttribute(&coop, hipDeviceAttributeCooperativeLaunch, dev);
  int nCU = 0;  (void)hipDeviceGetAttribute(&nCU, hipDeviceAttributeMultiprocessorCount, dev);
  int mb = 0;
  (void)hipOccupancyMaxActiveBlocksPerMultiprocessor(&mb, (const void*)k_fused, 256, 0);
  long long cap = (long long)mb * (long long)nCU;
  int G = (int)(cap > 1024 ? 1024 : cap);

  if (coop && G >= 64) {
    void* args[] = {
      (void*)&x, (void*)&ei, (void*)&W, (void*)&a, (void*)&gamma, (void*)&beta,
      (void*)&out, (void*)&hm, (void*)&hout, (void*)&s, (void*)&pack,
      (void*)&bins, (void*)&flag, (void*)&row_cnt, (void*)&row_src
    };
    hipError_t err = hipLaunchCooperativeKernel((const void*)k_fused, dim3(G),
                                                dim3(256), args, 0, stream);
    if (err == hipSuccess) return;
    (void)hipGetLastError();   // clear sticky error, fall through
  }
  sk_prep<<<32, 256, 0, stream>>>(W, a, (const int*)ei, pack, flag, row_cnt, bins);
  sk_gemm<<<MROWS / 16, 256, 0, stream>>>(x, pack, ei, flag, hm, s, row_cnt, row_src);
  sk_agg<<<NN, 256, 0, stream>>>(row_cnt, row_src, s, (const uint32*)hm, hout, bins);
  sk_elu<<<1024, 256, 0, stream>>>(hout, bins, gamma, beta, out);
}

// Round 9
// 201.279 us; speedup vs baseline: 1.3164x; 1.3164x over previous
//
#include <hip/hip_runtime.h>
#include <hip/hip_bf16.h>
#include <hip/hip_cooperative_groups.h>
#include <math.h>

namespace cg = cooperative_groups;

#define BB 8
#define NN 2048
#define INC 256
#define CC 128
#define NE 65536
#define CAP 128
#define MROWS (BB*NN)
#define BN_EPS 1e-5f
#define NT 9              // output col-tiles of 16 (8 -> hm, 1 -> s+pad)
#define NKC 8             // K chunks of 32 (K=256)
#define NFRAG (NT*NKC*64) // 4608 pre-packed fragments (72 KB)
#define FPSCALE 4194304.0 // 2^22 fixed-point scale for deterministic BN atomics
#define SMEM_BYTES 22912

typedef unsigned int uint32;
typedef unsigned long long u64;
typedef __attribute__((ext_vector_type(8))) short short8;
typedef __attribute__((ext_vector_type(4))) float f32x4;

__device__ inline ushort f2bf(float f) {
  __hip_bfloat16 b = __float2bfloat16(f);   // HW cvt, RNE
  return reinterpret_cast<ushort&>(b);
}
__device__ inline float bf2f(ushort h) {
  return __uint_as_float(((uint32)h) << 16);
}

__device__ inline void load_edge(const void* ei, int is64, int e, int& s, int& d) {
  if (is64) {
    const long long* p = (const long long*)ei;
    s = (int)p[e]; d = (int)p[NE + e];
  } else {
    const int* p = (const int*)ei;
    s = p[e]; d = p[NE + e];
  }
}

__device__ inline float edge_e(f32x4 ss, f32x4 sd) {
  float sum = 0.0f;
  #pragma unroll
  for (int h = 0; h < 4; ++h) {
    float v = ss[h] + sd[h];
    sum += (v > 0.0f) ? v : 0.2f * v;
  }
  return 0.25f * sum;
}

// ============ phase 0: W -> packed MFMA frags; detect int64; zero cnt/bins ===
// block m (0..31) owns input rows [8m,8m+8) == frag k-slice (kc=m>>2, g=m&3).
__device__ inline void phase0_prep(char* smem, int m, int tid,
                                   const float* __restrict__ W,
                                   const float* __restrict__ a,
                                   const int* __restrict__ ei32,
                                   uint4* __restrict__ pack,
                                   int* __restrict__ flag,
                                   int* __restrict__ row_cnt,
                                   u64* __restrict__ bins) {
  float (*Wl)[520]  = (float(*)[520])(smem);            // 16640 B
  float (*Wms)[132] = (float(*)[132])(smem + 16640);    //  4224 B
  float (*Was)[8]   = (float(*)[8])(smem + 20864);      //   256 B
  float* av         = (float*)(smem + 21120);           //  1024 B
  if (m < 8) row_cnt[m * 256 + tid] = 0;
  if (m == 8) {
    #pragma unroll
    for (int i = 0; i < 8; ++i) bins[tid * 8 + i] = 0ull;
  }
  if (m == 0 && tid == 0) {
    int nz = 0;
    for (int t = 1; t < 128; t += 2) nz |= (ei32[t] != 0);
    *flag = nz ? 0 : 1;      // 1 => int64 layout
  }
  av[tid] = a[tid];
  const float4* Wg = (const float4*)(W + (size_t)m * 8 * 512);
  #pragma unroll
  for (int i = 0; i < 4; ++i) {
    int idx = tid + i * 256;           // 0..1023 float4s = 8 rows x 128
    int r = idx >> 7, c4 = idx & 127;
    *(float4*)&Wl[r][c4 * 4] = Wg[idx];
  }
  __syncthreads();
  {
    int c = tid & 127, half = tid >> 7;
    #pragma unroll
    for (int ii = 0; ii < 4; ++ii) {
      int r = half * 4 + ii;
      Wms[r][c] = 0.25f * (Wl[r][c] + Wl[r][128 + c] + Wl[r][256 + c] + Wl[r][384 + c]);
    }
  }
  {
    int i8 = tid >> 5, c2 = tid & 31;
    float p[8];
    #pragma unroll
    for (int j = 0; j < 8; ++j) p[j] = 0.0f;
    #pragma unroll
    for (int t4 = 0; t4 < 4; ++t4) {
      int cc = c2 + t4 * 32;
      float asrc = av[cc], adst = av[128 + cc];
      #pragma unroll
      for (int h = 0; h < 4; ++h) {
        float w = Wl[i8][h * 128 + cc];
        p[h] += w * asrc;
        p[4 + h] += w * adst;
      }
    }
    #pragma unroll
    for (int off = 16; off > 0; off >>= 1)
      #pragma unroll
      for (int j = 0; j < 8; ++j) p[j] += __shfl_xor(p[j], off, 64);
    if (c2 < 8) Was[i8][c2] = p[c2];
  }
  __syncthreads();
  if (tid < 144) {
    int t = tid >> 4, l16 = tid & 15;
    int cch = t * 16 + l16;
    int kc = m >> 2, g = m & 3;
    uint32 h[8];
    #pragma unroll
    for (int j = 0; j < 8; ++j) {
      float v = 0.0f;
      if (cch < CC) v = Wms[j][cch];
      else if (cch < CC + 8) v = Was[j][cch - CC];
      h[j] = (uint32)f2bf(v);
    }
    uint4 u;
    u.x = h[0] | (h[1] << 16);
    u.y = h[2] | (h[3] << 16);
    u.z = h[4] | (h[5] << 16);
    u.w = h[6] | (h[7] << 16);
    pack[(t * NKC + kc) * 64 + g * 16 + l16] = u;
  }
}

// ============ phase 1: MFMA GEMM for one 16-row tile =========================
// hm(bf16)[16384][128] = x @ Wm ; s(f32)[16384][8] = x @ Wa.
// 4 waves: wave wv computes tiles {2wv,2wv+1}; wave 3 also tile 8 (E).
__device__ inline void phase1_gemm(int tile, int tid,
                                   const float* __restrict__ x,
                                   const uint4* __restrict__ pack,
                                   ushort* __restrict__ hm,
                                   float* __restrict__ s) {
  int lane = tid & 63, wv = tid >> 6;
  int g = lane >> 4;
  int xrow = tile * 16 + (lane & 15);
  const float* xr = x + (size_t)xrow * INC;
  short8 xf[8];
  #pragma unroll
  for (int kc = 0; kc < 8; ++kc) {
    f32x4 xa = *(const f32x4*)(xr + kc * 32 + g * 8);
    f32x4 xb = *(const f32x4*)(xr + kc * 32 + g * 8 + 4);
    short8 t;
    t[0] = (short)f2bf(xa[0]); t[1] = (short)f2bf(xa[1]);
    t[2] = (short)f2bf(xa[2]); t[3] = (short)f2bf(xa[3]);
    t[4] = (short)f2bf(xb[0]); t[5] = (short)f2bf(xb[1]);
    t[6] = (short)f2bf(xb[2]); t[7] = (short)f2bf(xb[3]);
    xf[kc] = t;
  }
  int t0 = wv * 2;
  f32x4 acc0 = (f32x4)(0.0f), acc1 = (f32x4)(0.0f), accE = (f32x4)(0.0f);
  const short8* fr = (const short8*)pack;
  #pragma unroll
  for (int kc = 0; kc < NKC; ++kc) {
    short8 af0 = fr[((t0 + 0) * NKC + kc) * 64 + lane];
    acc0 = __builtin_amdgcn_mfma_f32_16x16x32_bf16(af0, xf[kc], acc0, 0, 0, 0);
    short8 af1 = fr[((t0 + 1) * NKC + kc) * 64 + lane];
    acc1 = __builtin_amdgcn_mfma_f32_16x16x32_bf16(af1, xf[kc], acc1, 0, 0, 0);
    if (wv == 3) {
      short8 ae = fr[(8 * NKC + kc) * 64 + lane];
      accE = __builtin_amdgcn_mfma_f32_16x16x32_bf16(ae, xf[kc], accE, 0, 0, 0);
    }
  }
  // D layout: row(ch-in-tile) = 4*g + reg, col = lane&15
  ushort* hrow = hm + (size_t)xrow * CC;
  uint32 p0 = (uint32)f2bf(acc0[0]) | ((uint32)f2bf(acc0[1]) << 16);
  uint32 p1 = (uint32)f2bf(acc0[2]) | ((uint32)f2bf(acc0[3]) << 16);
  *(uint2*)(hrow + (t0 + 0) * 16 + g * 4) = make_uint2(p0, p1);
  p0 = (uint32)f2bf(acc1[0]) | ((uint32)f2bf(acc1[1]) << 16);
  p1 = (uint32)f2bf(acc1[2]) | ((uint32)f2bf(acc1[3]) << 16);
  *(uint2*)(hrow + (t0 + 1) * 16 + g * 4) = make_uint2(p0, p1);
  if (wv == 3 && g < 2) {
    *(f32x4*)(s + (size_t)xrow * 8 + g * 4) = accE;
  }
}

// ============ phase 2: dedupe+sort+e+softmax+aggregate+BN-partials (1 row) ===
__device__ inline void phase2_agg(char* smem, int d, int tid,
                                  const int* __restrict__ row_cnt,
                                  const int* __restrict__ row_src,
                                  const float* __restrict__ s,
                                  const uint32* __restrict__ hm32,
                                  uint32* __restrict__ hout,
                                  u64* __restrict__ bins) {
  int*   rsrc = (int*)(smem);                         //  512 B
  int*   csrc = (int*)(smem + 512);                   //  512 B
  float (*swgt)[CAP] = (float(*)[CAP])(smem + 1024);  // 4096 B
  f32x4* red  = (f32x4*)(smem + 5120);                // 4096 B
  int*   wcnt = (int*)(smem + 9216);                  //    8 B
  int lane = tid & 63, wv = tid >> 6;
  __syncthreads();   // guard smem reuse across calls
  int k0 = row_cnt[d]; if (k0 > CAP) k0 = CAP;
  if (tid < k0) rsrc[tid] = row_src[d * CAP + tid];
  __syncthreads();
  // dedupe by src (duplicate (src,dst) edges have identical e-values)
  int keep = 0;
  if (tid < k0) {
    keep = 1;
    int sv = rsrc[tid];
    for (int q = 0; q < tid; ++q) if (rsrc[q] == sv) { keep = 0; break; }
  }
  u64 mask = __ballot(keep);
  int pos = __popcll(mask & ((1ull << lane) - 1ull));
  if (lane == 0 && wv < 2) wcnt[wv] = (int)__popcll(mask);
  __syncthreads();
  int base = (wv == 1) ? wcnt[0] : 0;
  if (keep) csrc[base + pos] = rsrc[tid];
  __syncthreads();
  int kd = wcnt[0] + wcnt[1];
  // rank-sort by src value (unique) -> deterministic reduction order
  if (tid < kd) {
    int sv = csrc[tid], r = 0;
    for (int q = 0; q < kd; ++q) r += (csrc[q] < sv) ? 1 : 0;
    rsrc[r] = sv;
  }
  __syncthreads();

  int b0 = wv, b1 = wv + 4;
  const float* sb0 = s + (size_t)b0 * NN * 8;
  const float* sb1 = s + (size_t)b1 * NN * 8;
  f32x4 sd0 = *(const f32x4*)(sb0 + (size_t)d * 8 + 4);
  f32x4 sd1 = *(const f32x4*)(sb1 + (size_t)d * 8 + 4);
  float v00 = -INFINITY, v01 = -INFINITY, v10 = -INFINITY, v11 = -INFINITY;
  if (lane < kd) {
    int r = rsrc[lane];
    f32x4 s0 = *(const f32x4*)(sb0 + (size_t)r * 8);
    f32x4 s1 = *(const f32x4*)(sb1 + (size_t)r * 8);
    v00 = edge_e(s0, sd0);
    v10 = edge_e(s1, sd1);
  }
  if (lane + 64 < kd) {
    int r = rsrc[lane + 64];
    f32x4 s0 = *(const f32x4*)(sb0 + (size_t)r * 8);
    f32x4 s1 = *(const f32x4*)(sb1 + (size_t)r * 8);
    v01 = edge_e(s0, sd0);
    v11 = edge_e(s1, sd1);
  }
  float m0 = fmaxf(v00, v01), m1 = fmaxf(v10, v11);
  #pragma unroll
  for (int off = 32; off > 0; off >>= 1) {
    m0 = fmaxf(m0, __shfl_xor(m0, off, 64));
    m1 = fmaxf(m1, __shfl_xor(m1, off, 64));
  }
  float e00 = (lane < kd)      ? expf(v00 - m0) : 0.0f;
  float e01 = (lane + 64 < kd) ? expf(v01 - m0) : 0.0f;
  float e10 = (lane < kd)      ? expf(v10 - m1) : 0.0f;
  float e11 = (lane + 64 < kd) ? expf(v11 - m1) : 0.0f;
  float sum0 = e00 + e01, sum1 = e10 + e11;
  #pragma unroll
  for (int off = 32; off > 0; off >>= 1) {
    sum0 += __shfl_xor(sum0, off, 64);
    sum1 += __shfl_xor(sum1, off, 64);
  }
  float inv0 = (kd > 0) ? 1.0f / sum0 : 0.0f;
  float inv1 = (kd > 0) ? 1.0f / sum1 : 0.0f;
  swgt[b0][lane]      = e00 * inv0;
  swgt[b0][lane + 64] = e01 * inv0;
  swgt[b1][lane]      = e10 * inv1;
  swgt[b1][lane + 64] = e11 * inv1;

  float a0 = 0.0f, a1 = 0.0f, a2 = 0.0f, a3 = 0.0f;
  const uint32* hb0 = hm32 + (size_t)b0 * NN * (CC / 2);
  const uint32* hb1 = hm32 + (size_t)b1 * NN * (CC / 2);
  #pragma unroll 4
  for (int j = 0; j < kd; ++j) {
    int r = rsrc[j];
    float w0 = swgt[b0][j], w1 = swgt[b1][j];
    uint32 u0 = hb0[(size_t)r * (CC / 2) + lane];
    uint32 u1 = hb1[(size_t)r * (CC / 2) + lane];
    a0 += w0 * bf2f((ushort)(u0 & 0xffffu));
    a1 += w0 * bf2f((ushort)(u0 >> 16));
    a2 += w1 * bf2f((ushort)(u1 & 0xffffu));
    a3 += w1 * bf2f((ushort)(u1 >> 16));
  }
  hout[((size_t)b0 * NN + d) * (CC / 2) + lane] =
      (uint32)f2bf(a0) | ((uint32)f2bf(a1) << 16);
  hout[((size_t)b1 * NN + d) * (CC / 2) + lane] =
      (uint32)f2bf(a2) | ((uint32)f2bf(a3) << 16);

  // block-reduce BN partials, fixed-point i64 atomics (deterministic)
  f32x4 r4;
  r4[0] = a0 + a2; r4[1] = a0 * a0 + a2 * a2;
  r4[2] = a1 + a3; r4[3] = a1 * a1 + a3 * a3;
  red[tid] = r4;
  __syncthreads();
  if (wv == 0) {
    f32x4 t = red[lane] + red[lane + 64] + red[lane + 128] + red[lane + 192];
    u64* bb = bins + (size_t)(d & 7) * (CC * 2);
    atomicAdd(&bb[4 * lane + 0], (u64)(long long)llrint((double)t[0] * FPSCALE));
    atomicAdd(&bb[4 * lane + 1], (u64)(long long)llrint((double)t[1] * FPSCALE));
    atomicAdd(&bb[4 * lane + 2], (u64)(long long)llrint((double)t[2] * FPSCALE));
    atomicAdd(&bb[4 * lane + 3], (u64)(long long)llrint((double)t[3] * FPSCALE));
  }
}

// ============ phase 3: BN finalize (redundant/block) + ELU ===================
__device__ inline void phase3_bn(char* smem, int tid,
                                 const u64* __restrict__ bins,
                                 const float* __restrict__ gamma,
                                 const float* __restrict__ beta) {
  float* bsc = (float*)(smem);
  float* bsh = (float*)(smem + 512);
  if (tid < CC) {
    long long S = 0, Q = 0;
    #pragma unroll
    for (int bin = 0; bin < 8; ++bin) {
      S += (long long)bins[bin * (CC * 2) + 2 * tid];
      Q += (long long)bins[bin * (CC * 2) + 2 * tid + 1];
    }
    double mean = (double)S / FPSCALE / (double)MROWS;
    double var  = (double)Q / FPSCALE / (double)MROWS - mean * mean;
    if (var < 0.0) var = 0.0;
    float scale = gamma[tid] / sqrtf((float)var + BN_EPS);
    bsc[tid] = scale;
    bsh[tid] = beta[tid] - (float)mean * scale;
  }
  __syncthreads();
}
__device__ inline void phase3_elu(char* smem, int pp, int tid,
                                  const uint32* __restrict__ hout,
                                  float* __restrict__ out) {
  float* bsc = (float*)(smem);
  float* bsh = (float*)(smem + 512);
  int pbase = pp * 1024 + tid;
  #pragma unroll
  for (int i = 0; i < 4; ++i) {
    int p = pbase + i * 256;      // pair index
    int cp = p & 63;
    uint32 u = hout[p];
    float y0 = bf2f((ushort)(u & 0xffffu)) * bsc[2 * cp]     + bsh[2 * cp];
    float y1 = bf2f((ushort)(u >> 16))     * bsc[2 * cp + 1] + bsh[2 * cp + 1];
    float2 o;
    o.x = (y0 > 0.0f) ? y0 : expm1f(y0);
    o.y = (y1 > 0.0f) ? y1 : expm1f(y1);
    *(float2*)(out + 2 * (size_t)p) = o;
  }
}

// ============ fused cooperative kernel (grid-size agnostic) ==================
// NOTE: no min-occupancy hint — R8's __launch_bounds__(256,4) forced 64 VGPRs
// and massive scratch spilling (WRITE_SIZE 75 MB vs 18 MB legit, VALUBusy 2.8%).
__global__ __launch_bounds__(256) void k_fused(
    const float* __restrict__ x, const void* __restrict__ ei,
    const float* __restrict__ W, const float* __restrict__ a,
    const float* __restrict__ gamma, const float* __restrict__ beta,
    float* __restrict__ out,
    ushort* __restrict__ hm, uint32* __restrict__ hout,
    float* __restrict__ s, uint4* __restrict__ pack,
    u64* __restrict__ bins, int* __restrict__ flag,
    int* __restrict__ row_cnt, int* __restrict__ row_src) {
  cg::grid_group grid = cg::this_grid();
  __shared__ __align__(16) char smem[SMEM_BYTES];
  int blk = blockIdx.x, tid = threadIdx.x, G = gridDim.x;

  if (blk < 32)
    phase0_prep(smem, blk, tid, W, a, (const int*)ei, pack, flag, row_cnt, bins);
  grid.sync();

  {
    int is64 = *flag;
    for (int c = blk; c < NE / 256; c += G) {
      int e = c * 256 + tid;
      int src, dst;
      load_edge(ei, is64, e, src, dst);
      int pos = atomicAdd(&row_cnt[dst], 1);
      if (pos < CAP) row_src[dst * CAP + pos] = src;
    }
  }
  for (int tile = blk; tile < MROWS / 16; tile += G)
    phase1_gemm(tile, tid, x, pack, hm, s);
  grid.sync();

  for (int d = blk; d < NN; d += G)
    phase2_agg(smem, d, tid, row_cnt, row_src, s, (const uint32*)hm, hout, bins);
  grid.sync();

  phase3_bn(smem, tid, bins, gamma, beta);
  for (int pp = blk; pp < 1024; pp += G)
    phase3_elu(smem, pp, tid, hout, out);
}

// ============ fallback standalone kernels (same phase functions) =============
__global__ __launch_bounds__(256) void sk_prep(const float* __restrict__ W,
                                               const float* __restrict__ a,
                                               const int* __restrict__ ei32,
                                               uint4* __restrict__ pack,
                                               int* __restrict__ flag,
                                               int* __restrict__ row_cnt,
                                               u64* __restrict__ bins) {
  __shared__ __align__(16) char smem[SMEM_BYTES];
  phase0_prep(smem, blockIdx.x, threadIdx.x, W, a, ei32, pack, flag, row_cnt, bins);
}
__global__ __launch_bounds__(256) void sk_gemm(const float* __restrict__ x,
                                               const uint4* __restrict__ pack,
                                               const void* __restrict__ ei,
                                               const int* __restrict__ flag,
                                               ushort* __restrict__ hm,
                                               float* __restrict__ s,
                                               int* __restrict__ row_cnt,
                                               int* __restrict__ row_src) {
  if (threadIdx.x < 64) {
    int e = blockIdx.x * 64 + threadIdx.x;
    int is64 = *flag;
    int src, dst;
    load_edge(ei, is64, e, src, dst);
    int pos = atomicAdd(&row_cnt[dst], 1);
    if (pos < CAP) row_src[dst * CAP + pos] = src;
  }
  phase1_gemm(blockIdx.x, threadIdx.x, x, pack, hm, s);
}
__global__ __launch_bounds__(256) void sk_agg(const int* __restrict__ row_cnt,
                                              const int* __restrict__ row_src,
                                              const float* __restrict__ s,
                                              const uint32* __restrict__ hm32,
                                              uint32* __restrict__ hout,
                                              u64* __restrict__ bins) {
  __shared__ __align__(16) char smem[9224];
  phase2_agg(smem, blockIdx.x, threadIdx.x, row_cnt, row_src, s, hm32, hout, bins);
}
__global__ __launch_bounds__(256) void sk_elu(const uint32* __restrict__ hout,
                                              const u64* __restrict__ bins,
                                              const float* __restrict__ gamma,
                                              const float* __restrict__ beta,
                                              float* __restrict__ out) {
  __shared__ __align__(16) char smem[1024];
  phase3_bn(smem, threadIdx.x, bins, gamma, beta);
  phase3_elu(smem, blockIdx.x, threadIdx.x, hout, out);
}

extern "C" void kernel_launch(void* const* d_in, const int* in_sizes, int n_in,
                              void* d_out, int out_size, void* d_ws, size_t ws_size,
                              hipStream_t stream) {
  const float* x     = (const float*)d_in[0];
  const void*  ei    = d_in[1];
  const float* W     = (const float*)d_in[2];
  const float* a     = (const float*)d_in[3];
  const float* gamma = (const float*)d_in[4];
  const float* beta  = (const float*)d_in[5];
  float* out = (float*)d_out;

  char* p = (char*)d_ws;
  ushort* hm   = (ushort*)p; p += (size_t)MROWS * CC * 2;  // 4 MB (bf16)
  uint32* hout = (uint32*)p; p += (size_t)MROWS * CC * 2;  // 4 MB (bf16 pairs)
  float* s    = (float*)p; p += (size_t)MROWS * 8 * 4;     // 512 KB
  uint4* pack = (uint4*)p; p += (size_t)NFRAG * 16;        // 72 KB
  u64* bins   = (u64*)p;   p += 8 * CC * 2 * 8;            // 16 KB
  int* flag   = (int*)p;   p += 256;
  int* row_cnt  = (int*)p; p += NN * 4;
  int* row_src  = (int*)p; p += (size_t)NN * CAP * 4;      // 1 MB

  // host-side, capture-safe queries; deterministic on a given device
  int dev = 0; (void)hipGetDevice(&dev);
  int coop = 0; (void)hipDeviceGetAttribute(&coop, hipDeviceAttributeCooperativeLaunch, dev);
  int nCU = 0;  (void)hipDeviceGetAttribute(&nCU, hipDeviceAttributeMultiprocessorCount, dev);
  int mb = 0;
  (void)hipOccupancyMaxActiveBlocksPerMultiprocessor(&mb, (const void*)k_fused, 256, 0);
  long long cap = (long long)mb * (long long)nCU;
  int G = (int)(cap > 1024 ? 1024 : cap);

  if (coop && G >= 64) {
    void* args[] = {
      (void*)&x, (void*)&ei, (void*)&W, (void*)&a, (void*)&gamma, (void*)&beta,
      (void*)&out, (void*)&hm, (void*)&hout, (void*)&s, (void*)&pack,
      (void*)&bins, (void*)&flag, (void*)&row_cnt, (void*)&row_src
    };
    hipError_t err = hipLaunchCooperativeKernel((const void*)k_fused, dim3(G),
                                                dim3(256), args, 0, stream);
    if (err == hipSuccess) return;
    (void)hipGetLastError();   // clear sticky error, fall through
  }
  sk_prep<<<32, 256, 0, stream>>>(W, a, (const int*)ei, pack, flag, row_cnt, bins);
  sk_gemm<<<MROWS / 16, 256, 0, stream>>>(x, pack, ei, flag, hm, s, row_cnt, row_src);
  sk_agg<<<NN, 256, 0, stream>>>(row_cnt, row_src, s, (const uint32*)hm, hout, bins);
  sk_elu<<<1024, 256, 0, stream>>>(hout, bins, gamma, beta, out);
}

// Round 10
// 88.557 us; speedup vs baseline: 2.9921x; 2.2729x over previous
//
#include <hip/hip_runtime.h>
#include <hip/hip_bf16.h>
#include <math.h>

#define BB 8
#define NN 2048
#define INC 256
#define CC 128
#define NE 65536
#define CAP 128
#define MROWS (BB*NN)
#define BN_EPS 1e-5f
#define NT 9              // output col-tiles of 16 (8 -> hm, 1 -> s+pad)
#define NKC 8             // K chunks of 32 (K=256)
#define NFRAG (NT*NKC*64) // 4608 pre-packed fragments (72 KB)
#define FPSCALE 4194304.0 // 2^22 fixed-point scale for deterministic BN atomics

typedef unsigned int uint32;
typedef unsigned long long u64;
typedef __attribute__((ext_vector_type(8))) short short8;
typedef __attribute__((ext_vector_type(4))) float f32x4;

__device__ inline ushort f2bf(float f) {
  __hip_bfloat16 b = __float2bfloat16(f);   // HW cvt, RNE
  return reinterpret_cast<ushort&>(b);
}
__device__ inline float bf2f(ushort h) {
  return __uint_as_float(((uint32)h) << 16);
}

__device__ inline void load_edge(const void* ei, int is64, int e, int& s, int& d) {
  if (is64) {
    const long long* p = (const long long*)ei;
    s = (int)p[e]; d = (int)p[NE + e];
  } else {
    const int* p = (const int*)ei;
    s = p[e]; d = p[NE + e];
  }
}

__device__ inline float edge_e(f32x4 ss, f32x4 sd) {
  float sum = 0.0f;
  #pragma unroll
  for (int h = 0; h < 4; ++h) {
    float v = ss[h] + sd[h];
    sum += (v > 0.0f) ? v : 0.2f * v;
  }
  return 0.25f * sum;
}

// ---- prep: W -> packed MFMA fragments; detect int64; zero row_cnt + bins ----
// block m owns input rows [8m, 8m+8) == fragment k-slice (kc=m>>2, g=m&3).
__global__ __launch_bounds__(256) void k_prep(const float* __restrict__ W,
                                              const float* __restrict__ a,
                                              const int* __restrict__ ei32,
                                              uint4* __restrict__ pack,
                                              int* __restrict__ flag,
                                              int* __restrict__ row_cnt,
                                              u64* __restrict__ bins) {
  __shared__ float Wl[8][520];
  __shared__ float Wms[8][132];
  __shared__ float Was[8][8];
  __shared__ float av[256];
  int m = blockIdx.x, tid = threadIdx.x;
  if (m < 8) row_cnt[m * 256 + tid] = 0;
  if (m == 8) {
    #pragma unroll
    for (int i = 0; i < 8; ++i) bins[tid * 8 + i] = 0ull;
  }
  if (m == 0 && tid == 0) {
    int nz = 0;
    for (int t = 1; t < 128; t += 2) nz |= (ei32[t] != 0);
    *flag = nz ? 0 : 1;      // 1 => int64 layout
  }
  av[tid] = a[tid];
  const float4* Wg = (const float4*)(W + (size_t)m * 8 * 512);
  #pragma unroll
  for (int i = 0; i < 4; ++i) {
    int idx = tid + i * 256;           // 0..1023 float4s = 8 rows x 128
    int r = idx >> 7, c4 = idx & 127;
    *(float4*)&Wl[r][c4 * 4] = Wg[idx];
  }
  __syncthreads();
  {
    int c = tid & 127, half = tid >> 7;
    #pragma unroll
    for (int ii = 0; ii < 4; ++ii) {
      int r = half * 4 + ii;
      Wms[r][c] = 0.25f * (Wl[r][c] + Wl[r][128 + c] + Wl[r][256 + c] + Wl[r][384 + c]);
    }
  }
  {
    int i8 = tid >> 5, c2 = tid & 31;
    float p[8];
    #pragma unroll
    for (int j = 0; j < 8; ++j) p[j] = 0.0f;
    #pragma unroll
    for (int t4 = 0; t4 < 4; ++t4) {
      int cc = c2 + t4 * 32;
      float asrc = av[cc], adst = av[128 + cc];
      #pragma unroll
      for (int h = 0; h < 4; ++h) {
        float w = Wl[i8][h * 128 + cc];
        p[h] += w * asrc;
        p[4 + h] += w * adst;
      }
    }
    #pragma unroll
    for (int off = 16; off > 0; off >>= 1)
      #pragma unroll
      for (int j = 0; j < 8; ++j) p[j] += __shfl_xor(p[j], off, 64);
    if (c2 < 8) Was[i8][c2] = p[c2];
  }
  __syncthreads();
  if (tid < 144) {
    int t = tid >> 4, l16 = tid & 15;
    int cch = t * 16 + l16;
    int kc = m >> 2, g = m & 3;
    uint32 h[8];
    #pragma unroll
    for (int j = 0; j < 8; ++j) {
      float v = 0.0f;
      if (cch < CC) v = Wms[j][cch];
      else if (cch < CC + 8) v = Was[j][cch - CC];
      h[j] = (uint32)f2bf(v);
    }
    uint4 u;
    u.x = h[0] | (h[1] << 16);
    u.y = h[2] | (h[3] << 16);
    u.z = h[4] | (h[5] << 16);
    u.w = h[6] | (h[7] << 16);
    pack[(t * NKC + kc) * 64 + g * 16 + l16] = u;
  }
}

// ---- MFMA GEMM + edge-list build ----
// hm(bf16) NODE-MAJOR [node][b][128] ; s(f32) [node][b][8] ; row lists from ei.
// 512 threads = 8 waves: row-tile rt=wv&3, t-half th=wv>>2; pack staged in LDS.
__global__ __launch_bounds__(512) void k_gemm(const float* __restrict__ x,
                                              const uint4* __restrict__ pack,
                                              const void* __restrict__ ei,
                                              const int* __restrict__ flag,
                                              ushort* __restrict__ hm,
                                              float* __restrict__ s,
                                              int* __restrict__ row_cnt,
                                              int* __restrict__ row_src) {
  __shared__ uint4 lp[NFRAG];   // 72 KB
  int tid = threadIdx.x;
  // edge-list build: this block's 256 edges
  if (tid < 256) {
    int e = blockIdx.x * 256 + tid;
    int is64 = *flag;
    int src, dst;
    load_edge(ei, is64, e, src, dst);
    int pos = atomicAdd(&row_cnt[dst], 1);
    if (pos < CAP) row_src[dst * CAP + pos] = src;
  }
  // stage fragments -> LDS (9 sweeps x 8 KB)
  #pragma unroll
  for (int i = 0; i < 9; ++i) lp[i * 512 + tid] = pack[i * 512 + tid];

  int lane = tid & 63, wv = tid >> 6;
  int rt = wv & 3, th = wv >> 2;
  int g = lane >> 4;
  int xrow = blockIdx.x * 64 + rt * 16 + (lane & 15);
  int b = xrow >> 11, n = xrow & (NN - 1);
  const float* xr = x + (size_t)xrow * INC;

  short8 xf[8];
  #pragma unroll
  for (int kc = 0; kc < 8; ++kc) {
    f32x4 xa = *(const f32x4*)(xr + kc * 32 + g * 8);
    f32x4 xb = *(const f32x4*)(xr + kc * 32 + g * 8 + 4);
    short8 t;
    t[0] = (short)f2bf(xa[0]); t[1] = (short)f2bf(xa[1]);
    t[2] = (short)f2bf(xa[2]); t[3] = (short)f2bf(xa[3]);
    t[4] = (short)f2bf(xb[0]); t[5] = (short)f2bf(xb[1]);
    t[6] = (short)f2bf(xb[2]); t[7] = (short)f2bf(xb[3]);
    xf[kc] = t;
  }
  __syncthreads();

  f32x4 acc[4];
  f32x4 accE = (f32x4)(0.0f);
  #pragma unroll
  for (int i = 0; i < 4; ++i) acc[i] = (f32x4)(0.0f);

  const short8* fr = (const short8*)lp;
  int tb = th * 4;
  #pragma unroll
  for (int kc = 0; kc < NKC; ++kc) {
    #pragma unroll
    for (int i = 0; i < 4; ++i) {
      short8 af = fr[((tb + i) * NKC + kc) * 64 + lane];
      acc[i] = __builtin_amdgcn_mfma_f32_16x16x32_bf16(af, xf[kc], acc[i], 0, 0, 0);
    }
    short8 ae = fr[(8 * NKC + kc) * 64 + lane];
    accE = __builtin_amdgcn_mfma_f32_16x16x32_bf16(ae, xf[kc], accE, 0, 0, 0);
  }

  // D layout: row(ch-in-tile) = 4*g + reg, col(xrow-in-wave) = lane&15
  ushort* hrow = hm + ((size_t)n * BB + b) * CC;
  #pragma unroll
  for (int i = 0; i < 4; ++i) {
    int t = tb + i;
    uint32 p0 = (uint32)f2bf(acc[i][0]) | ((uint32)f2bf(acc[i][1]) << 16);
    uint32 p1 = (uint32)f2bf(acc[i][2]) | ((uint32)f2bf(acc[i][3]) << 16);
    *(uint2*)(hrow + t * 16 + g * 4) = make_uint2(p0, p1);
  }
  if (th == 1 && g < 2) {
    *(f32x4*)(s + ((size_t)n * BB + b) * 8 + g * 4) = accE;
  }
}

// ---- fused dedupe+sort+e+softmax+aggregate+BN-partials: one block per dst row ----
// softmax: wave wv handles batches (wv, wv+4); gather: thread = (b=tid>>5, 4 ch).
__global__ __launch_bounds__(256) void k_agg(const int* __restrict__ row_cnt,
                                             const int* __restrict__ row_src,
                                             const float* __restrict__ s,
                                             const uint2* __restrict__ hm2,
                                             uint2* __restrict__ hout2,
                                             u64* __restrict__ bins) {
  __shared__ int rsrc[CAP], csrc[CAP];
  __shared__ float swgt[8][CAP];
  __shared__ f32x4 redS[256];
  __shared__ f32x4 redQ[256];
  __shared__ int wcnt[2];
  int d = blockIdx.x, tid = threadIdx.x;
  int lane = tid & 63, wv = tid >> 6;
  int k0 = row_cnt[d]; if (k0 > CAP) k0 = CAP;

  if (tid < k0) rsrc[tid] = row_src[d * CAP + tid];
  __syncthreads();
  // dedupe by src (duplicate (src,dst) edges have identical e-values; set suffices)
  int keep = 0;
  if (tid < k0) {
    keep = 1;
    int sv = rsrc[tid];
    for (int q = 0; q < tid; ++q) if (rsrc[q] == sv) { keep = 0; break; }
  }
  u64 mask = __ballot(keep);
  int pos = __popcll(mask & ((1ull << lane) - 1ull));
  if (lane == 0 && wv < 2) wcnt[wv] = (int)__popcll(mask);
  __syncthreads();
  int base = (wv == 1) ? wcnt[0] : 0;
  if (keep) csrc[base + pos] = rsrc[tid];
  __syncthreads();
  int kd = wcnt[0] + wcnt[1];
  // rank-sort by src value (unique) -> deterministic reduction order
  if (tid < kd) {
    int sv = csrc[tid], r = 0;
    for (int q = 0; q < kd; ++q) r += (csrc[q] < sv) ? 1 : 0;
    rsrc[r] = sv;
  }
  __syncthreads();

  // ---- softmax weights: wave wv computes batches b0=wv, b1=wv+4 ----
  {
    int b0 = wv, b1 = wv + 4;
    f32x4 sd0 = *(const f32x4*)(s + ((size_t)d * BB + b0) * 8 + 4);
    f32x4 sd1 = *(const f32x4*)(s + ((size_t)d * BB + b1) * 8 + 4);
    float v00 = -INFINITY, v01 = -INFINITY, v10 = -INFINITY, v11 = -INFINITY;
    if (lane < kd) {
      int r = rsrc[lane];
      f32x4 s0 = *(const f32x4*)(s + ((size_t)r * BB + b0) * 8);
      f32x4 s1 = *(const f32x4*)(s + ((size_t)r * BB + b1) * 8);
      v00 = edge_e(s0, sd0);
      v10 = edge_e(s1, sd1);
    }
    if (lane + 64 < kd) {
      int r = rsrc[lane + 64];
      f32x4 s0 = *(const f32x4*)(s + ((size_t)r * BB + b0) * 8);
      f32x4 s1 = *(const f32x4*)(s + ((size_t)r * BB + b1) * 8);
      v01 = edge_e(s0, sd0);
      v11 = edge_e(s1, sd1);
    }
    float m0 = fmaxf(v00, v01), m1 = fmaxf(v10, v11);
    #pragma unroll
    for (int off = 32; off > 0; off >>= 1) {
      m0 = fmaxf(m0, __shfl_xor(m0, off, 64));
      m1 = fmaxf(m1, __shfl_xor(m1, off, 64));
    }
    float e00 = (lane < kd)      ? expf(v00 - m0) : 0.0f;
    float e01 = (lane + 64 < kd) ? expf(v01 - m0) : 0.0f;
    float e10 = (lane < kd)      ? expf(v10 - m1) : 0.0f;
    float e11 = (lane + 64 < kd) ? expf(v11 - m1) : 0.0f;
    float sum0 = e00 + e01, sum1 = e10 + e11;
    #pragma unroll
    for (int off = 32; off > 0; off >>= 1) {
      sum0 += __shfl_xor(sum0, off, 64);
      sum1 += __shfl_xor(sum1, off, 64);
    }
    float inv0 = (kd > 0) ? 1.0f / sum0 : 0.0f;
    float inv1 = (kd > 0) ? 1.0f / sum1 : 0.0f;
    swgt[b0][lane]      = e00 * inv0;
    swgt[b0][lane + 64] = e01 * inv0;
    swgt[b1][lane]      = e10 * inv1;
    swgt[b1][lane + 64] = e11 * inv1;
  }
  __syncthreads();

  // ---- gather: whole block reads node r's 2 KB (all batches) per j ----
  int b = tid >> 5;                 // batch
  int q32 = tid & 31;               // which uint2 (4 channels) within batch row
  float ac0 = 0, ac1 = 0, ac2 = 0, ac3 = 0;
  #pragma unroll 4
  for (int j = 0; j < kd; ++j) {
    int r = rsrc[j];
    float w = swgt[b][j];
    uint2 u = hm2[(size_t)r * 256 + tid];   // coalesced 2 KB per block
    ac0 += w * bf2f((ushort)(u.x & 0xffffu));
    ac1 += w * bf2f((ushort)(u.x >> 16));
    ac2 += w * bf2f((ushort)(u.y & 0xffffu));
    ac3 += w * bf2f((ushort)(u.y >> 16));
  }
  uint2 o;
  o.x = (uint32)f2bf(ac0) | ((uint32)f2bf(ac1) << 16);
  o.y = (uint32)f2bf(ac2) | ((uint32)f2bf(ac3) << 16);
  hout2[((size_t)b * NN + d) * 32 + q32] = o;

  // ---- BN partials: reduce across 8 batches, fixed-point i64 atomics ----
  f32x4 rs, rq;
  rs[0] = ac0; rs[1] = ac1; rs[2] = ac2; rs[3] = ac3;
  rq[0] = ac0 * ac0; rq[1] = ac1 * ac1; rq[2] = ac2 * ac2; rq[3] = ac3 * ac3;
  redS[tid] = rs; redQ[tid] = rq;
  __syncthreads();
  if (tid < 32) {
    f32x4 ts = redS[tid], tq = redQ[tid];
    #pragma unroll
    for (int k = 1; k < 8; ++k) { ts += redS[tid + 32 * k]; tq += redQ[tid + 32 * k]; }
    u64* bb = bins + (size_t)(d & 7) * (CC * 2);
    int cb = tid * 4;
    #pragma unroll
    for (int i = 0; i < 4; ++i) {
      atomicAdd(&bb[2 * (cb + i) + 0], (u64)(long long)llrint((double)ts[i] * FPSCALE));
      atomicAdd(&bb[2 * (cb + i) + 1], (u64)(long long)llrint((double)tq[i] * FPSCALE));
    }
  }
}

// ---- BN finalize (per-block, redundant) + normalize + ELU ----
__global__ __launch_bounds__(256) void k_elu(const uint32* __restrict__ hout,
                                             const u64* __restrict__ bins,
                                             const float* __restrict__ gamma,
                                             const float* __restrict__ beta,
                                             float* __restrict__ out) {
  __shared__ float bsc[CC], bsh[CC];
  int tid = threadIdx.x;
  if (tid < CC) {
    long long S = 0, Q = 0;
    #pragma unroll
    for (int bin = 0; bin < 8; ++bin) {
      S += (long long)bins[bin * (CC * 2) + 2 * tid];
      Q += (long long)bins[bin * (CC * 2) + 2 * tid + 1];
    }
    double mean = (double)S / FPSCALE / (double)MROWS;
    double var  = (double)Q / FPSCALE / (double)MROWS - mean * mean;
    if (var < 0.0) var = 0.0;
    float scale = gamma[tid] / sqrtf((float)var + BN_EPS);
    bsc[tid] = scale;
    bsh[tid] = beta[tid] - (float)mean * scale;
  }
  __syncthreads();
  int pbase = blockIdx.x * 1024 + tid;
  #pragma unroll
  for (int i = 0; i < 4; ++i) {
    int p = pbase + i * 256;      // pair index
    int cp = p & 63;
    uint32 u = hout[p];
    float y0 = bf2f((ushort)(u & 0xffffu)) * bsc[2 * cp]     + bsh[2 * cp];
    float y1 = bf2f((ushort)(u >> 16))     * bsc[2 * cp + 1] + bsh[2 * cp + 1];
    float2 o;
    o.x = (y0 > 0.0f) ? y0 : expm1f(y0);
    o.y = (y1 > 0.0f) ? y1 : expm1f(y1);
    *(float2*)(out + 2 * (size_t)p) = o;
  }
}

extern "C" void kernel_launch(void* const* d_in, const int* in_sizes, int n_in,
                              void* d_out, int out_size, void* d_ws, size_t ws_size,
                              hipStream_t stream) {
  const float* x     = (const float*)d_in[0];
  const void*  ei    = d_in[1];
  const float* W     = (const float*)d_in[2];
  const float* a     = (const float*)d_in[3];
  const float* gamma = (const float*)d_in[4];
  const float* beta  = (const float*)d_in[5];
  float* out = (float*)d_out;

  char* p = (char*)d_ws;
  ushort* hm   = (ushort*)p; p += (size_t)MROWS * CC * 2;  // 4 MB (bf16, node-major)
  uint32* hout = (uint32*)p; p += (size_t)MROWS * CC * 2;  // 4 MB (bf16 pairs)
  float* s    = (float*)p; p += (size_t)MROWS * 8 * 4;     // 512 KB (node-major)
  uint4* pack = (uint4*)p; p += (size_t)NFRAG * 16;        // 72 KB
  u64* bins   = (u64*)p;   p += 8 * CC * 2 * 8;            // 16 KB
  int* flag   = (int*)p;   p += 256;
  int* row_cnt  = (int*)p; p += NN * 4;
  int* row_src  = (int*)p; p += (size_t)NN * CAP * 4;      // 1 MB

  k_prep<<<32, 256, 0, stream>>>(W, a, (const int*)ei, pack, flag, row_cnt, bins);
  k_gemm<<<MROWS / 64, 512, 0, stream>>>(x, pack, ei, flag, hm, s, row_cnt, row_src);
  k_agg<<<NN, 256, 0, stream>>>(row_cnt, row_src, s, (const uint2*)hm,
                                (uint2*)hout, bins);
  k_elu<<<(MROWS * CC / 2) / 1024, 256, 0, stream>>>(hout, bins, gamma, beta, out);
}

// Round 11
// 63.320 us; speedup vs baseline: 4.1846x; 1.3986x over previous
//
#include <hip/hip_runtime.h>
#include <hip/hip_bf16.h>
#include <math.h>

#define BB 8
#define NN 2048
#define INC 256
#define CC 128
#define NE 65536
#define CAP 128
#define MROWS (BB*NN)
#define BN_EPS 1e-5f
#define NT 9              // output col-tiles of 16 (8 -> hm, 1 -> s+pad)
#define NKC 8             // K chunks of 32 (K=256)
#define NFRAG (NT*NKC*64) // 4608 pre-packed fragments (72 KB)
#define FPSCALE 4194304.0 // 2^22 fixed-point scale for deterministic BN atomics

typedef unsigned int uint32;
typedef unsigned long long u64;
typedef __attribute__((ext_vector_type(8))) short short8;
typedef __attribute__((ext_vector_type(4))) float f32x4;

__device__ inline ushort f2bf(float f) {
  __hip_bfloat16 b = __float2bfloat16(f);   // HW cvt, RNE
  return reinterpret_cast<ushort&>(b);
}
__device__ inline float bf2f(ushort h) {
  return __uint_as_float(((uint32)h) << 16);
}

__device__ inline void load_edge(const void* ei, int is64, int e, int& s, int& d) {
  if (is64) {
    const long long* p = (const long long*)ei;
    s = (int)p[e]; d = (int)p[NE + e];
  } else {
    const int* p = (const int*)ei;
    s = p[e]; d = p[NE + e];
  }
}

// ---- prep: W -> packed MFMA fragments; detect int64; zero row_cnt + bins ----
// block m owns input rows [8m, 8m+8) == fragment k-slice (kc=m>>2, g=m&3).
__global__ __launch_bounds__(256) void k_prep(const float* __restrict__ W,
                                              const float* __restrict__ a,
                                              const int* __restrict__ ei32,
                                              uint4* __restrict__ pack,
                                              int* __restrict__ flag,
                                              int* __restrict__ row_cnt,
                                              u64* __restrict__ bins) {
  __shared__ float Wl[8][520];
  __shared__ float Wms[8][132];
  __shared__ float Was[8][8];
  __shared__ float av[256];
  int m = blockIdx.x, tid = threadIdx.x;
  if (m < 8) row_cnt[m * 256 + tid] = 0;
  if (m == 8) {
    #pragma unroll
    for (int i = 0; i < 8; ++i) bins[tid * 8 + i] = 0ull;
  }
  if (m == 0 && tid == 0) {
    int nz = 0;
    for (int t = 1; t < 128; t += 2) nz |= (ei32[t] != 0);
    *flag = nz ? 0 : 1;      // 1 => int64 layout
  }
  av[tid] = a[tid];
  const float4* Wg = (const float4*)(W + (size_t)m * 8 * 512);
  #pragma unroll
  for (int i = 0; i < 4; ++i) {
    int idx = tid + i * 256;           // 0..1023 float4s = 8 rows x 128
    int r = idx >> 7, c4 = idx & 127;
    *(float4*)&Wl[r][c4 * 4] = Wg[idx];
  }
  __syncthreads();
  {
    int c = tid & 127, half = tid >> 7;
    #pragma unroll
    for (int ii = 0; ii < 4; ++ii) {
      int r = half * 4 + ii;
      Wms[r][c] = 0.25f * (Wl[r][c] + Wl[r][128 + c] + Wl[r][256 + c] + Wl[r][384 + c]);
    }
  }
  {
    int i8 = tid >> 5, c2 = tid & 31;
    float p[8];
    #pragma unroll
    for (int j = 0; j < 8; ++j) p[j] = 0.0f;
    #pragma unroll
    for (int t4 = 0; t4 < 4; ++t4) {
      int cc = c2 + t4 * 32;
      float asrc = av[cc], adst = av[128 + cc];
      #pragma unroll
      for (int h = 0; h < 4; ++h) {
        float w = Wl[i8][h * 128 + cc];
        p[h] += w * asrc;
        p[4 + h] += w * adst;
      }
    }
    #pragma unroll
    for (int off = 16; off > 0; off >>= 1)
      #pragma unroll
      for (int j = 0; j < 8; ++j) p[j] += __shfl_xor(p[j], off, 64);
    if (c2 < 8) Was[i8][c2] = p[c2];
  }
  __syncthreads();
  if (tid < 144) {
    int t = tid >> 4, l16 = tid & 15;
    int cch = t * 16 + l16;
    int kc = m >> 2, g = m & 3;
    uint32 h[8];
    #pragma unroll
    for (int j = 0; j < 8; ++j) {
      float v = 0.0f;
      if (cch < CC) v = Wms[j][cch];
      else if (cch < CC + 8) v = Was[j][cch - CC];
      h[j] = (uint32)f2bf(v);
    }
    uint4 u;
    u.x = h[0] | (h[1] << 16);
    u.y = h[2] | (h[3] << 16);
    u.z = h[4] | (h[5] << 16);
    u.w = h[6] | (h[7] << 16);
    pack[(t * NKC + kc) * 64 + g * 16 + l16] = u;
  }
}

// ---- MFMA GEMM + edge-list build (R6 structure, batch-major outputs) ----
// 512 threads = 8 waves: row-tile rt=wv&3 (16 rows), t-half th=wv>>2.
// pack staged once into LDS; 2 blocks/CU -> 16 waves/CU.
__global__ __launch_bounds__(512) void k_gemm(const float* __restrict__ x,
                                              const uint4* __restrict__ pack,
                                              const void* __restrict__ ei,
                                              const int* __restrict__ flag,
                                              ushort* __restrict__ hm,
                                              float* __restrict__ s,
                                              int* __restrict__ row_cnt,
                                              int* __restrict__ row_src) {
  __shared__ uint4 lp[NFRAG];   // 72 KB
  int tid = threadIdx.x;
  // edge-list build: this block's 256 edges
  if (tid < 256) {
    int e = blockIdx.x * 256 + tid;
    int is64 = *flag;
    int src, dst;
    load_edge(ei, is64, e, src, dst);
    int pos = atomicAdd(&row_cnt[dst], 1);
    if (pos < CAP) row_src[dst * CAP + pos] = src;
  }
  // stage fragments -> LDS (9 sweeps x 8 KB)
  #pragma unroll
  for (int i = 0; i < 9; ++i) lp[i * 512 + tid] = pack[i * 512 + tid];

  int lane = tid & 63, wv = tid >> 6;
  int rt = wv & 3, th = wv >> 2;
  int g = lane >> 4;
  int xrow = blockIdx.x * 64 + rt * 16 + (lane & 15);
  const float* xr = x + (size_t)xrow * INC;

  short8 xf[8];
  #pragma unroll
  for (int kc = 0; kc < 8; ++kc) {
    f32x4 xa = *(const f32x4*)(xr + kc * 32 + g * 8);
    f32x4 xb = *(const f32x4*)(xr + kc * 32 + g * 8 + 4);
    short8 t;
    t[0] = (short)f2bf(xa[0]); t[1] = (short)f2bf(xa[1]);
    t[2] = (short)f2bf(xa[2]); t[3] = (short)f2bf(xa[3]);
    t[4] = (short)f2bf(xb[0]); t[5] = (short)f2bf(xb[1]);
    t[6] = (short)f2bf(xb[2]); t[7] = (short)f2bf(xb[3]);
    xf[kc] = t;
  }
  __syncthreads();

  f32x4 acc[4];
  f32x4 accE = (f32x4)(0.0f);
  #pragma unroll
  for (int i = 0; i < 4; ++i) acc[i] = (f32x4)(0.0f);

  const short8* fr = (const short8*)lp;
  int tb = th * 4;
  #pragma unroll
  for (int kc = 0; kc < NKC; ++kc) {
    #pragma unroll
    for (int i = 0; i < 4; ++i) {
      short8 af = fr[((tb + i) * NKC + kc) * 64 + lane];
      acc[i] = __builtin_amdgcn_mfma_f32_16x16x32_bf16(af, xf[kc], acc[i], 0, 0, 0);
    }
    short8 ae = fr[(8 * NKC + kc) * 64 + lane];
    accE = __builtin_amdgcn_mfma_f32_16x16x32_bf16(ae, xf[kc], accE, 0, 0, 0);
  }

  // D layout: row(ch-in-tile) = 4*g + reg, col(xrow-in-wave) = lane&15
  ushort* hrow = hm + (size_t)xrow * CC;
  #pragma unroll
  for (int i = 0; i < 4; ++i) {
    int t = tb + i;
    uint32 p0 = (uint32)f2bf(acc[i][0]) | ((uint32)f2bf(acc[i][1]) << 16);
    uint32 p1 = (uint32)f2bf(acc[i][2]) | ((uint32)f2bf(acc[i][3]) << 16);
    *(uint2*)(hrow + t * 16 + g * 4) = make_uint2(p0, p1);
  }
  if (th == 1 && g < 2) {
    *(f32x4*)(s + (size_t)xrow * 8 + g * 4) = accE;
  }
}

__device__ inline float edge_e(f32x4 ss, f32x4 sd) {
  float sum = 0.0f;
  #pragma unroll
  for (int h = 0; h < 4; ++h) {
    float v = ss[h] + sd[h];
    sum += (v > 0.0f) ? v : 0.2f * v;
  }
  return 0.25f * sum;
}

// ---- fused dedupe+sort+e+softmax+aggregate+BN-partials: one block per dst row ----
// R6 structure (dual-stream gather) + O(1) bitmask dedupe (replaces the serial
// O(tid) scan: last wave did ~255 LDS-read iters; now one LDS atomicOr).
// Nondeterministic atomic winner is OK: survivors are unique VALUES, and the
// rank-sort by value makes the final list deterministic.
__global__ __launch_bounds__(256) void k_agg(const int* __restrict__ row_cnt,
                                             const int* __restrict__ row_src,
                                             const float* __restrict__ s,
                                             const uint32* __restrict__ hm32,
                                             uint32* __restrict__ hout,
                                             u64* __restrict__ bins) {
  __shared__ int rsrc[CAP], csrc[CAP];
  __shared__ float swgt[8][CAP];
  __shared__ f32x4 red[256];
  __shared__ uint32 bmask[64];     // 2048-bit node mask
  __shared__ int wcnt[2];
  int d = blockIdx.x, tid = threadIdx.x;
  int lane = tid & 63, wv = tid >> 6;
  int k0 = row_cnt[d]; if (k0 > CAP) k0 = CAP;

  if (tid < 64) bmask[tid] = 0u;
  if (tid < k0) rsrc[tid] = row_src[d * CAP + tid];
  __syncthreads();
  // dedupe by src via bitmask (duplicate (src,dst) edges have identical e-values)
  int keep = 0;
  if (tid < k0) {
    int sv = rsrc[tid];
    uint32 bit = 1u << (sv & 31);
    uint32 old = atomicOr(&bmask[sv >> 5], bit);
    keep = ((old & bit) == 0) ? 1 : 0;
  }
  u64 mask = __ballot(keep);
  int pos = __popcll(mask & ((1ull << lane) - 1ull));
  if (lane == 0 && wv < 2) wcnt[wv] = (int)__popcll(mask);
  __syncthreads();
  int base = (wv == 1) ? wcnt[0] : 0;
  if (keep) csrc[base + pos] = rsrc[tid];
  __syncthreads();
  int kd = wcnt[0] + wcnt[1];
  // rank-sort by src value (unique) -> deterministic reduction order
  if (tid < kd) {
    int sv = csrc[tid], r = 0;
    for (int q = 0; q < kd; ++q) r += (csrc[q] < sv) ? 1 : 0;
    rsrc[r] = sv;
  }
  __syncthreads();

  int b0 = wv, b1 = wv + 4;
  const float* sb0 = s + (size_t)b0 * NN * 8;
  const float* sb1 = s + (size_t)b1 * NN * 8;
  f32x4 sd0 = *(const f32x4*)(sb0 + (size_t)d * 8 + 4);
  f32x4 sd1 = *(const f32x4*)(sb1 + (size_t)d * 8 + 4);
  float v00 = -INFINITY, v01 = -INFINITY, v10 = -INFINITY, v11 = -INFINITY;
  if (lane < kd) {
    int r = rsrc[lane];
    f32x4 s0 = *(const f32x4*)(sb0 + (size_t)r * 8);
    f32x4 s1 = *(const f32x4*)(sb1 + (size_t)r * 8);
    v00 = edge_e(s0, sd0);
    v10 = edge_e(s1, sd1);
  }
  if (lane + 64 < kd) {
    int r = rsrc[lane + 64];
    f32x4 s0 = *(const f32x4*)(sb0 + (size_t)r * 8);
    f32x4 s1 = *(const f32x4*)(sb1 + (size_t)r * 8);
    v01 = edge_e(s0, sd0);
    v11 = edge_e(s1, sd1);
  }
  float m0 = fmaxf(v00, v01), m1 = fmaxf(v10, v11);
  #pragma unroll
  for (int off = 32; off > 0; off >>= 1) {
    m0 = fmaxf(m0, __shfl_xor(m0, off, 64));
    m1 = fmaxf(m1, __shfl_xor(m1, off, 64));
  }
  float e00 = (lane < kd)      ? expf(v00 - m0) : 0.0f;
  float e01 = (lane + 64 < kd) ? expf(v01 - m0) : 0.0f;
  float e10 = (lane < kd)      ? expf(v10 - m1) : 0.0f;
  float e11 = (lane + 64 < kd) ? expf(v11 - m1) : 0.0f;
  float sum0 = e00 + e01, sum1 = e10 + e11;
  #pragma unroll
  for (int off = 32; off > 0; off >>= 1) {
    sum0 += __shfl_xor(sum0, off, 64);
    sum1 += __shfl_xor(sum1, off, 64);
  }
  float inv0 = (kd > 0) ? 1.0f / sum0 : 0.0f;
  float inv1 = (kd > 0) ? 1.0f / sum1 : 0.0f;
  swgt[b0][lane]      = e00 * inv0;
  swgt[b0][lane + 64] = e01 * inv0;
  swgt[b1][lane]      = e10 * inv1;
  swgt[b1][lane + 64] = e11 * inv1;

  float a0 = 0.0f, a1 = 0.0f, a2 = 0.0f, a3 = 0.0f;
  const uint32* hb0 = hm32 + (size_t)b0 * NN * (CC / 2);
  const uint32* hb1 = hm32 + (size_t)b1 * NN * (CC / 2);
  #pragma unroll 4
  for (int j = 0; j < kd; ++j) {
    int r = rsrc[j];
    float w0 = swgt[b0][j], w1 = swgt[b1][j];
    uint32 u0 = hb0[(size_t)r * (CC / 2) + lane];
    uint32 u1 = hb1[(size_t)r * (CC / 2) + lane];
    a0 += w0 * bf2f((ushort)(u0 & 0xffffu));
    a1 += w0 * bf2f((ushort)(u0 >> 16));
    a2 += w1 * bf2f((ushort)(u1 & 0xffffu));
    a3 += w1 * bf2f((ushort)(u1 >> 16));
  }
  hout[((size_t)b0 * NN + d) * (CC / 2) + lane] =
      (uint32)f2bf(a0) | ((uint32)f2bf(a1) << 16);
  hout[((size_t)b1 * NN + d) * (CC / 2) + lane] =
      (uint32)f2bf(a2) | ((uint32)f2bf(a3) << 16);

  // block-reduce BN partials, fixed-point i64 atomic into bin d&7 (deterministic)
  f32x4 r4;
  r4[0] = a0 + a2; r4[1] = a0 * a0 + a2 * a2;
  r4[2] = a1 + a3; r4[3] = a1 * a1 + a3 * a3;
  red[tid] = r4;
  __syncthreads();
  if (wv == 0) {
    f32x4 t = red[lane] + red[lane + 64] + red[lane + 128] + red[lane + 192];
    u64* bb = bins + (size_t)(d & 7) * (CC * 2);
    atomicAdd(&bb[4 * lane + 0], (u64)(long long)llrint((double)t[0] * FPSCALE));
    atomicAdd(&bb[4 * lane + 1], (u64)(long long)llrint((double)t[1] * FPSCALE));
    atomicAdd(&bb[4 * lane + 2], (u64)(long long)llrint((double)t[2] * FPSCALE));
    atomicAdd(&bb[4 * lane + 3], (u64)(long long)llrint((double)t[3] * FPSCALE));
  }
}

// ---- BN finalize (per-block, redundant) + normalize + ELU ----
__global__ __launch_bounds__(256) void k_elu(const uint32* __restrict__ hout,
                                             const u64* __restrict__ bins,
                                             const float* __restrict__ gamma,
                                             const float* __restrict__ beta,
                                             float* __restrict__ out) {
  __shared__ float bsc[CC], bsh[CC];
  int tid = threadIdx.x;
  if (tid < CC) {
    long long S = 0, Q = 0;
    #pragma unroll
    for (int bin = 0; bin < 8; ++bin) {
      S += (long long)bins[bin * (CC * 2) + 2 * tid];
      Q += (long long)bins[bin * (CC * 2) + 2 * tid + 1];
    }
    double mean = (double)S / FPSCALE / (double)MROWS;
    double var  = (double)Q / FPSCALE / (double)MROWS - mean * mean;
    if (var < 0.0) var = 0.0;
    float scale = gamma[tid] / sqrtf((float)var + BN_EPS);
    bsc[tid] = scale;
    bsh[tid] = beta[tid] - (float)mean * scale;
  }
  __syncthreads();
  int pbase = blockIdx.x * 1024 + tid;
  #pragma unroll
  for (int i = 0; i < 4; ++i) {
    int p = pbase + i * 256;      // pair index
    int cp = p & 63;
    uint32 u = hout[p];
    float y0 = bf2f((ushort)(u & 0xffffu)) * bsc[2 * cp]     + bsh[2 * cp];
    float y1 = bf2f((ushort)(u >> 16))     * bsc[2 * cp + 1] + bsh[2 * cp + 1];
    float2 o;
    o.x = (y0 > 0.0f) ? y0 : expm1f(y0);
    o.y = (y1 > 0.0f) ? y1 : expm1f(y1);
    *(float2*)(out + 2 * (size_t)p) = o;
  }
}

extern "C" void kernel_launch(void* const* d_in, const int* in_sizes, int n_in,
                              void* d_out, int out_size, void* d_ws, size_t ws_size,
                              hipStream_t stream) {
  const float* x     = (const float*)d_in[0];
  const void*  ei    = d_in[1];
  const float* W     = (const float*)d_in[2];
  const float* a     = (const float*)d_in[3];
  const float* gamma = (const float*)d_in[4];
  const float* beta  = (const float*)d_in[5];
  float* out = (float*)d_out;

  char* p = (char*)d_ws;
  ushort* hm   = (ushort*)p; p += (size_t)MROWS * CC * 2;  // 4 MB (bf16)
  uint32* hout = (uint32*)p; p += (size_t)MROWS * CC * 2;  // 4 MB (bf16 pairs)
  float* s    = (float*)p; p += (size_t)MROWS * 8 * 4;     // 512 KB
  uint4* pack = (uint4*)p; p += (size_t)NFRAG * 16;        // 72 KB
  u64* bins   = (u64*)p;   p += 8 * CC * 2 * 8;            // 16 KB
  int* flag   = (int*)p;   p += 256;
  int* row_cnt  = (int*)p; p += NN * 4;
  int* row_src  = (int*)p; p += (size_t)NN * CAP * 4;      // 1 MB

  k_prep<<<32, 256, 0, stream>>>(W, a, (const int*)ei, pack, flag, row_cnt, bins);
  k_gemm<<<MROWS / 64, 512, 0, stream>>>(x, pack, ei, flag, hm, s, row_cnt, row_src);
  k_agg<<<NN, 256, 0, stream>>>(row_cnt, row_src, s, (const uint32*)hm, hout, bins);
  k_elu<<<(MROWS * CC / 2) / 1024, 256, 0, stream>>>(hout, bins, gamma, beta, out);
}